// Round 11
// baseline (392.064 us; speedup 1.0000x reference)
//
#include <hip/hip_runtime.h>
#include <hip/hip_fp16.h>

#define N_NODES 100000
#define N_EDGES 1600000
#define HDIM 64
#define NPB 256                                   // nodes per bucket (pow2)
#define NPB_SHIFT 8
#define NBUCK 391                                 // ceil(100000/256)
#define GRID_B 256                                // setup grid blocks (1/CU, co-resident)
#define NCHUNK 256                                // edge chunks (== GRID_B)
#define CHUNK (N_EDGES / NCHUNK)                  // 6250
#define NTASK (2 * NBUCK)                         // 782 bucket tasks (dst + src)

// ---- manual grid barrier: safe because GRID_B=256 blocks of 4 waves/4KB LDS
// ---- all fit co-resident on 256 CUs (capacity >> grid), so every block is
// ---- dispatched before any spins. Counters pre-zeroed via hipMemsetAsync.
__device__ __forceinline__ void grid_barrier(int* cnt, int id) {
    __syncthreads();
    if (threadIdx.x == 0) {
        __threadfence();
        __hip_atomic_fetch_add(&cnt[id], 1, __ATOMIC_RELEASE, __HIP_MEMORY_SCOPE_AGENT);
        while (__hip_atomic_load(&cnt[id], __ATOMIC_ACQUIRE, __HIP_MEMORY_SCOPE_AGENT) < GRID_B)
            __builtin_amdgcn_s_sleep(1);
        __threadfence();
    }
    __syncthreads();
}

// ---------------- fused setup: hist -> scan -> base -> place -> bucket dst/src ----------------
__global__ void __launch_bounds__(256)
setup_kernel(const int* __restrict__ src, const int* __restrict__ dst,
             int* __restrict__ hbD, int* __restrict__ hbS,
             int* __restrict__ pbD, int* __restrict__ pbS,
             int* __restrict__ totD, int* __restrict__ totS,
             int* __restrict__ baseD, int* __restrict__ baseS,
             unsigned int* __restrict__ bufD, unsigned char* __restrict__ bufS,
             int* __restrict__ csr_src, int* __restrict__ offsets,
             float* __restrict__ inv_in, float* __restrict__ inv_out,
             int* __restrict__ bar) {
    __shared__ int sm[1024];                      // 4 KB, aliased per phase
    int t = threadIdx.x, blk = blockIdx.x;
    int e0 = blk * CHUNK;

    // ---- Phase A: per-chunk bucket histograms ----
    {
        int* hD = sm;            // NBUCK
        int* hS = sm + NBUCK;    // NBUCK
        for (int i = t; i < 2 * NBUCK; i += 256) sm[i] = 0;
        __syncthreads();
        for (int i = t; i < CHUNK; i += 256) {
            atomicAdd(&hD[dst[e0 + i] >> NPB_SHIFT], 1);
            atomicAdd(&hS[src[e0 + i] >> NPB_SHIFT], 1);
        }
        __syncthreads();
        for (int i = t; i < NBUCK; i += 256) {
            hbD[i * NCHUNK + blk] = hD[i];
            hbS[i * NCHUNK + blk] = hS[i];
        }
    }
    grid_barrier(bar, 0);

    // ---- Phase B: per-bucket scan across chunks (782 tasks striped) ----
    for (int task = blk; task < NTASK; task += GRID_B) {
        const int* h; int* pb; int* tot; int b;
        if (task < NBUCK) { h = hbD; pb = pbD; tot = totD; b = task; }
        else              { h = hbS; pb = pbS; tot = totS; b = task - NBUCK; }
        int v = h[b * NCHUNK + t];
        sm[t] = v;
        __syncthreads();
        for (int off = 1; off < 256; off <<= 1) {
            int x = (t >= off) ? sm[t - off] : 0;
            __syncthreads(); sm[t] += x; __syncthreads();
        }
        pb[b * NCHUNK + t] = sm[t] - v;
        if (t == 255) tot[b] = sm[t];
        __syncthreads();
    }
    grid_barrier(bar, 1);

    // ---- Phase C: scan bucket totals -> bases (blocks 0 and 1) ----
    if (blk < 2) {
        const int* tot = blk ? totS : totD;
        int* base = blk ? baseS : baseD;
        int i0 = 2 * t, i1 = 2 * t + 1;
        int v0 = (i0 < NBUCK) ? tot[i0] : 0;
        int v1 = (i1 < NBUCK) ? tot[i1] : 0;
        int p = v0 + v1;
        sm[t] = p;
        __syncthreads();
        for (int off = 1; off < 256; off <<= 1) {
            int x = (t >= off) ? sm[t - off] : 0;
            __syncthreads(); sm[t] += x; __syncthreads();
        }
        int ep = sm[t] - p;
        if (i0 < NBUCK) base[i0] = ep;
        if (i1 < NBUCK) base[i1] = ep + v0;
    }
    grid_barrier(bar, 2);

    // ---- Phase D: place edges into bucket-partitioned staging ----
    {
        int* curD = sm;
        int* curS = sm + NBUCK;
        for (int i = t; i < NBUCK; i += 256) {
            curD[i] = baseD[i] + pbD[i * NCHUNK + blk];
            curS[i] = baseS[i] + pbS[i * NCHUNK + blk];
        }
        __syncthreads();
        for (int i = t; i < CHUNK; i += 256) {
            int s = src[e0 + i], d = dst[e0 + i];
            int pd = atomicAdd(&curD[d >> NPB_SHIFT], 1);
            bufD[pd] = (unsigned)s | ((unsigned)(d & (NPB - 1)) << 17);
            int ps = atomicAdd(&curS[s >> NPB_SHIFT], 1);
            bufS[ps] = (unsigned char)(s & (NPB - 1));
        }
    }
    grid_barrier(bar, 3);

    // ---- Phase E/F: per-bucket fine stage (dst: offsets/inv_in/csr_src; src: inv_out) ----
    {
        int* cnt = sm;
        int* pre = sm + 256;
        int* cur = sm + 512;
        for (int task = blk; task < NTASK; task += GRID_B) {
            __syncthreads();
            if (task < NBUCK) {
                int b = task, ebase = baseD[b], ecnt = totD[b];
                cnt[t] = 0;
                __syncthreads();
                for (int i = t; i < ecnt; i += 256)
                    atomicAdd(&cnt[(int)(bufD[ebase + i] >> 17)], 1);
                __syncthreads();
                int v = cnt[t];
                pre[t] = v;
                __syncthreads();
                for (int off = 1; off < 256; off <<= 1) {
                    int x = (t >= off) ? pre[t - off] : 0;
                    __syncthreads(); pre[t] += x; __syncthreads();
                }
                int excl = pre[t] - v;
                cur[t] = excl;
                int node = b * NPB + t;
                if (node < N_NODES) {
                    offsets[node] = ebase + excl;
                    inv_in[node] = rsqrtf((float)max(v, 1));
                } else if (node == N_NODES) {
                    offsets[N_NODES] = N_EDGES;
                }
                __syncthreads();
                for (int i = t; i < ecnt; i += 256) {
                    unsigned en = bufD[ebase + i];
                    int pos = atomicAdd(&cur[(int)(en >> 17)], 1);
                    csr_src[ebase + pos] = (int)(en & 0x1FFFFu);
                }
            } else {
                int b = task - NBUCK, ebase = baseS[b], ecnt = totS[b];
                cnt[t] = 0;
                __syncthreads();
                for (int i = t; i < ecnt; i += 256)
                    atomicAdd(&cnt[(int)bufS[ebase + i]], 1);
                __syncthreads();
                int node = b * NPB + t;
                if (node < N_NODES) inv_out[node] = rsqrtf((float)max(cnt[t], 1));
            }
        }
    }
}

__device__ inline uint2 f4_to_h4(float4 a) {
    __half2 lo = __floats2half2_rn(a.x, a.y);
    __half2 hi = __floats2half2_rn(a.z, a.w);
    uint2 r;
    r.x = *(unsigned*)&lo;
    r.y = *(unsigned*)&hi;
    return r;
}

// ---------------- dense: hw(fp16) = (h * inv_out[:,None]) @ W  (32 rows/block) ----------------
__global__ void dense_kernel(const float* __restrict__ h, const float* __restrict__ inv_out,
                             const float* __restrict__ W, uint2* __restrict__ hw, int n) {
    __shared__ float Wlds[HDIM * HDIM];     // 16 KB
    __shared__ float Alds[32][HDIM + 1];    // 8.1 KB
    int t = threadIdx.x;
    int r0 = blockIdx.x * 32;

    for (int i = t; i < HDIM * HDIM / 4; i += 256)
        ((float4*)Wlds)[i] = ((const float4*)W)[i];

    for (int i = t; i < 512; i += 256) {    // 32 rows x 16 float4
        int r = i >> 4;
        int c4 = i & 15;
        int row = r0 + r;
        float4 v = make_float4(0.f, 0.f, 0.f, 0.f);
        float s = 0.f;
        if (row < n) {
            v = ((const float4*)h)[(long long)row * 16 + c4];
            s = inv_out[row];
        }
        Alds[r][c4 * 4 + 0] = v.x * s;
        Alds[r][c4 * 4 + 1] = v.y * s;
        Alds[r][c4 * 4 + 2] = v.z * s;
        Alds[r][c4 * 4 + 3] = v.w * s;
    }
    __syncthreads();

    int tx = t & 15;        // col quad
    int ty = t >> 4;        // 16 row-pairs
    float4 acc0 = make_float4(0.f, 0.f, 0.f, 0.f);
    float4 acc1 = acc0;

#pragma unroll 8
    for (int k = 0; k < HDIM; ++k) {
        float4 w = ((const float4*)(Wlds + k * HDIM))[tx];
        float a0 = Alds[2 * ty + 0][k];
        float a1 = Alds[2 * ty + 1][k];
        acc0.x = fmaf(a0, w.x, acc0.x); acc0.y = fmaf(a0, w.y, acc0.y);
        acc0.z = fmaf(a0, w.z, acc0.z); acc0.w = fmaf(a0, w.w, acc0.w);
        acc1.x = fmaf(a1, w.x, acc1.x); acc1.y = fmaf(a1, w.y, acc1.y);
        acc1.z = fmaf(a1, w.z, acc1.z); acc1.w = fmaf(a1, w.w, acc1.w);
    }

    int rb = r0 + 2 * ty;
    if (rb + 0 < n) hw[(long long)(rb + 0) * 16 + tx] = f4_to_h4(acc0);
    if (rb + 1 < n) hw[(long long)(rb + 1) * 16 + tx] = f4_to_h4(acc1);
}

// ---------------- gather: out = relu(inv_in * sum_{in-edges} hw[src] + b) ----------------
// one 8-lane group per dst row (8 rows/wave, 32 rows/block); lane = 16B slice of the row.
__global__ void gather_kernel(const uint4* __restrict__ hw, const float* __restrict__ inv_in,
                              const int* __restrict__ offsets, const int* __restrict__ csr_src,
                              const float* __restrict__ bias, float* __restrict__ out, int n) {
    int t = threadIdx.x;
    int wave = t >> 6, lane = t & 63;
    int g = lane >> 3, gl = lane & 7;          // group 0..7, lane-in-group 0..7
    int row = blockIdx.x * 32 + wave * 8 + g;  // N = 3125 * 32 exactly
    if (row >= n) return;

    float acc0 = 0.f, acc1 = 0.f, acc2 = 0.f, acc3 = 0.f;
    float acc4 = 0.f, acc5 = 0.f, acc6 = 0.f, acc7 = 0.f;

    int start = offsets[row];
    int end   = offsets[row + 1];
    int gbase = g << 3;

    int jb = start;
    int mm = end - jb; if (mm > 8) mm = 8;
    int sidx = (mm > 0 && gl < mm) ? csr_src[jb + gl] : 0;

    while (jb < end) {
        int jb2 = jb + 8;
        int mm2 = end - jb2; if (mm2 > 8) mm2 = 8;
        int sidx2 = (jb2 < end && gl < mm2) ? csr_src[jb2 + gl] : 0;

        if (mm == 8) {
#pragma unroll
            for (int j = 0; j < 8; ++j) {
                int s = __shfl(sidx, gbase + j, 64);
                uint4 u = hw[(long long)s * 8 + gl];
                float2 f0 = __half22float2(*(__half2*)&u.x);
                float2 f1 = __half22float2(*(__half2*)&u.y);
                float2 f2 = __half22float2(*(__half2*)&u.z);
                float2 f3 = __half22float2(*(__half2*)&u.w);
                acc0 += f0.x; acc1 += f0.y; acc2 += f1.x; acc3 += f1.y;
                acc4 += f2.x; acc5 += f2.y; acc6 += f3.x; acc7 += f3.y;
            }
        } else {
            for (int j = 0; j < mm; ++j) {
                int s = __shfl(sidx, gbase + j, 64);
                uint4 u = hw[(long long)s * 8 + gl];
                float2 f0 = __half22float2(*(__half2*)&u.x);
                float2 f1 = __half22float2(*(__half2*)&u.y);
                float2 f2 = __half22float2(*(__half2*)&u.z);
                float2 f3 = __half22float2(*(__half2*)&u.w);
                acc0 += f0.x; acc1 += f0.y; acc2 += f1.x; acc3 += f1.y;
                acc4 += f2.x; acc5 += f2.y; acc6 += f3.x; acc7 += f3.y;
            }
        }
        jb = jb2; mm = mm2; sidx = sidx2;
    }

    float sc = inv_in[row];
    float4 b0 = ((const float4*)bias)[gl * 2 + 0];
    float4 b1 = ((const float4*)bias)[gl * 2 + 1];
    float4 r0, r1;
    r0.x = fmaxf(fmaf(acc0, sc, b0.x), 0.f);
    r0.y = fmaxf(fmaf(acc1, sc, b0.y), 0.f);
    r0.z = fmaxf(fmaf(acc2, sc, b0.z), 0.f);
    r0.w = fmaxf(fmaf(acc3, sc, b0.w), 0.f);
    r1.x = fmaxf(fmaf(acc4, sc, b1.x), 0.f);
    r1.y = fmaxf(fmaf(acc5, sc, b1.y), 0.f);
    r1.z = fmaxf(fmaf(acc6, sc, b1.z), 0.f);
    r1.w = fmaxf(fmaf(acc7, sc, b1.w), 0.f);
    ((float4*)out)[(long long)row * 16 + gl * 2 + 0] = r0;
    ((float4*)out)[(long long)row * 16 + gl * 2 + 1] = r1;
}

extern "C" void kernel_launch(void* const* d_in, const int* in_sizes, int n_in,
                              void* d_out, int out_size, void* d_ws, size_t ws_size,
                              hipStream_t stream) {
    const float* features = (const float*)d_in[0];   // [N, 64]
    const float* W        = (const float*)d_in[1];   // [64, 64]
    const float* b        = (const float*)d_in[2];   // [64]
    const int*   src      = (const int*)d_in[3];     // [E]
    const int*   dst      = (const int*)d_in[4];     // [E]

    float* out = (float*)d_out;                      // [N, 64] — also inter-layer temp

    // workspace layout (4-byte words); ~35 MB of 256 MB ws
    float* ws = (float*)d_ws;
    uint2* hw = (uint2*)ws;                                             // N*16 uint2 = 12.8 MB
    unsigned int*  bufD = (unsigned int*)(ws + (size_t)N_NODES * 32);   // E words (6.4 MB)
    unsigned char* bufS = (unsigned char*)(bufD + N_EDGES);             // E bytes (1.6 MB)
    float* inv_out = (float*)(bufS + N_EDGES);       // N
    float* inv_in  = inv_out + N_NODES;              // N
    int*   offsets = (int*)(inv_in + N_NODES);       // N+1
    int*   csr_src = offsets + N_NODES + 1;          // E
    int*   hbD     = csr_src + N_EDGES;              // NBUCK*NCHUNK
    int*   hbS     = hbD + NBUCK * NCHUNK;
    int*   pbD     = hbS + NBUCK * NCHUNK;
    int*   pbS     = pbD + NBUCK * NCHUNK;
    int*   totD    = pbS + NBUCK * NCHUNK;           // NBUCK
    int*   totS    = totD + NBUCK;                   // NBUCK
    int*   baseD   = totS + NBUCK;                   // NBUCK
    int*   baseS   = baseD + NBUCK;                  // NBUCK
    int*   bar     = baseS + NBUCK + 16;             // 16 ints (barrier counters)

    const int N = N_NODES;

    // zero barrier counters, then one fused setup kernel (replaces 6 kernels)
    hipMemsetAsync(bar, 0, 16 * sizeof(int), stream);
    setup_kernel<<<GRID_B, 256, 0, stream>>>(src, dst, hbD, hbS, pbD, pbS, totD, totS,
                                             baseD, baseS, bufD, bufS, csr_src, offsets,
                                             inv_in, inv_out, bar);

    int dense_blocks  = (N + 31) / 32;
    int gather_blocks = (N + 31) / 32;   // 32 rows per block

    // layer 1: features -> hw(fp16) -> out
    dense_kernel<<<dense_blocks, 256, 0, stream>>>(features, inv_out, W, hw, N);
    gather_kernel<<<gather_blocks, 256, 0, stream>>>((const uint4*)hw, inv_in, offsets, csr_src, b, out, N);

    // layer 2: out -> hw(fp16) -> out
    dense_kernel<<<dense_blocks, 256, 0, stream>>>(out, inv_out, W, hw, N);
    gather_kernel<<<gather_blocks, 256, 0, stream>>>((const uint4*)hw, inv_in, offsets, csr_src, b, out, N);
}

// Round 12
// 235.681 us; speedup vs baseline: 1.6635x; 1.6635x over previous
//
#include <hip/hip_runtime.h>
#include <hip/hip_fp16.h>

#define N_NODES 100000
#define N_EDGES 1600000
#define HDIM 64
#define NPB 512                                  // nodes per bucket (pow2)
#define NPB_SHIFT 9
#define NBUCK 196                                // ceil(100000/512)
#define CAP 16384                                // per-bucket slot capacity (mean 8163, ~90 sigma)
#define NCHUNK 256                               // place blocks
#define CHUNK (N_EDGES / NCHUNK)                 // 6250 edges/block

// ---------------- K0: init global bucket cursors ----------------
__global__ void init_kernel(int* __restrict__ gcurD, int* __restrict__ gcurS) {
    int t = threadIdx.x;
    if (t < NBUCK) {
        gcurD[t] = t * CAP;
        gcurS[t] = t * CAP;
    }
}

// ---------------- K1: place edges into fixed-capacity bucket regions ----------------
// Run reservation: one global atomic per (chunk,bucket); scatter via LDS cursors.
// bufD entry: src | (local_dst << 17)   (src < 2^17, local_dst < 512)
__global__ void place_kernel(const int* __restrict__ src, const int* __restrict__ dst,
                             int* __restrict__ gcurD, int* __restrict__ gcurS,
                             unsigned int* __restrict__ bufD, unsigned short* __restrict__ bufS) {
    __shared__ int hD[NBUCK], hS[NBUCK], curD[NBUCK], curS[NBUCK];
    int t = threadIdx.x, blk = blockIdx.x;
    for (int i = t; i < NBUCK; i += 256) { hD[i] = 0; hS[i] = 0; }
    __syncthreads();
    int e0 = blk * CHUNK;
    // pass 1: count (chunk is ~50 KB -> stays L1/L2 hot for pass 2)
    for (int i = t; i < CHUNK; i += 256) {
        atomicAdd(&hD[dst[e0 + i] >> NPB_SHIFT], 1);
        atomicAdd(&hS[src[e0 + i] >> NPB_SHIFT], 1);
    }
    __syncthreads();
    // reserve runs
    for (int i = t; i < NBUCK; i += 256) {
        curD[i] = hD[i] ? atomicAdd(&gcurD[i], hD[i]) : 0;
        curS[i] = hS[i] ? atomicAdd(&gcurS[i], hS[i]) : 0;
    }
    __syncthreads();
    // pass 2: scatter
    for (int i = t; i < CHUNK; i += 256) {
        int s = src[e0 + i], d = dst[e0 + i];
        int pd = atomicAdd(&curD[d >> NPB_SHIFT], 1);
        bufD[pd] = (unsigned)s | ((unsigned)(d & (NPB - 1)) << 17);
        int ps = atomicAdd(&curS[s >> NPB_SHIFT], 1);
        bufS[ps] = (unsigned short)(s & (NPB - 1));
    }
}

// ---------------- K2: merged per-bucket fine stage ----------------
// blocks [0,196): dst buckets -> counting sort to csr_src, offs(int2), inv_in
// blocks [196,392): src buckets -> counts -> inv_out
__global__ void bucket_kernel(const unsigned int* __restrict__ bufD,
                              const unsigned short* __restrict__ bufS,
                              const int* __restrict__ gcurD, const int* __restrict__ gcurS,
                              int* __restrict__ csr_src, int2* __restrict__ offs,
                              float* __restrict__ inv_in, float* __restrict__ inv_out) {
    __shared__ int cnt[NPB], pre[NPB], cur[NPB];
    int t = threadIdx.x;   // blockDim = 512
    int blk = blockIdx.x;
    if (blk < NBUCK) {
        int b = blk;
        int ebase = b * CAP;
        int ecnt  = gcurD[b] - ebase;
        cnt[t] = 0;
        __syncthreads();
        for (int i = t; i < ecnt; i += NPB)
            atomicAdd(&cnt[(int)(bufD[ebase + i] >> 17)], 1);
        __syncthreads();
        int v = cnt[t];
        pre[t] = v;
        __syncthreads();
        for (int off = 1; off < NPB; off <<= 1) {
            int x = (t >= off) ? pre[t - off] : 0;
            __syncthreads(); pre[t] += x; __syncthreads();
        }
        int excl = pre[t] - v;
        cur[t] = excl;
        int node = b * NPB + t;
        if (node < N_NODES) {
            offs[node] = make_int2(ebase + excl, ebase + excl + v);
            inv_in[node] = rsqrtf((float)max(v, 1));
        }
        __syncthreads();
        for (int i = t; i < ecnt; i += NPB) {
            unsigned en = bufD[ebase + i];
            int pos = atomicAdd(&cur[(int)(en >> 17)], 1);
            csr_src[ebase + pos] = (int)(en & 0x1FFFFu);
        }
    } else {
        int b = blk - NBUCK;
        int ebase = b * CAP;
        int ecnt  = gcurS[b] - ebase;
        cnt[t] = 0;
        __syncthreads();
        for (int i = t; i < ecnt; i += NPB)
            atomicAdd(&cnt[(int)bufS[ebase + i]], 1);
        __syncthreads();
        int node = b * NPB + t;
        if (node < N_NODES) inv_out[node] = rsqrtf((float)max(cnt[t], 1));
    }
}

__device__ inline uint2 f4_to_h4(float4 a) {
    __half2 lo = __floats2half2_rn(a.x, a.y);
    __half2 hi = __floats2half2_rn(a.z, a.w);
    uint2 r;
    r.x = *(unsigned*)&lo;
    r.y = *(unsigned*)&hi;
    return r;
}

// ---------------- dense: hw(fp16) = (h * inv_out[:,None]) @ W  (32 rows/block) ----------------
__global__ void dense_kernel(const float* __restrict__ h, const float* __restrict__ inv_out,
                             const float* __restrict__ W, uint2* __restrict__ hw, int n) {
    __shared__ float Wlds[HDIM * HDIM];     // 16 KB
    __shared__ float Alds[32][HDIM + 1];    // 8.1 KB
    int t = threadIdx.x;
    int r0 = blockIdx.x * 32;

    for (int i = t; i < HDIM * HDIM / 4; i += 256)
        ((float4*)Wlds)[i] = ((const float4*)W)[i];

    for (int i = t; i < 512; i += 256) {    // 32 rows x 16 float4
        int r = i >> 4;
        int c4 = i & 15;
        int row = r0 + r;
        float4 v = make_float4(0.f, 0.f, 0.f, 0.f);
        float s = 0.f;
        if (row < n) {
            v = ((const float4*)h)[(long long)row * 16 + c4];
            s = inv_out[row];
        }
        Alds[r][c4 * 4 + 0] = v.x * s;
        Alds[r][c4 * 4 + 1] = v.y * s;
        Alds[r][c4 * 4 + 2] = v.z * s;
        Alds[r][c4 * 4 + 3] = v.w * s;
    }
    __syncthreads();

    int tx = t & 15;        // col quad
    int ty = t >> 4;        // 16 row-pairs
    float4 acc0 = make_float4(0.f, 0.f, 0.f, 0.f);
    float4 acc1 = acc0;

#pragma unroll 8
    for (int k = 0; k < HDIM; ++k) {
        float4 w = ((const float4*)(Wlds + k * HDIM))[tx];
        float a0 = Alds[2 * ty + 0][k];
        float a1 = Alds[2 * ty + 1][k];
        acc0.x = fmaf(a0, w.x, acc0.x); acc0.y = fmaf(a0, w.y, acc0.y);
        acc0.z = fmaf(a0, w.z, acc0.z); acc0.w = fmaf(a0, w.w, acc0.w);
        acc1.x = fmaf(a1, w.x, acc1.x); acc1.y = fmaf(a1, w.y, acc1.y);
        acc1.z = fmaf(a1, w.z, acc1.z); acc1.w = fmaf(a1, w.w, acc1.w);
    }

    int rb = r0 + 2 * ty;
    if (rb + 0 < n) hw[(long long)(rb + 0) * 16 + tx] = f4_to_h4(acc0);
    if (rb + 1 < n) hw[(long long)(rb + 1) * 16 + tx] = f4_to_h4(acc1);
}

// ---------------- gather: out = relu(inv_in * sum_{in-edges} hw[src] + b) ----------------
// one 8-lane group per dst row (8 rows/wave, 32 rows/block); lane = 16B slice of the row.
__global__ void gather_kernel(const uint4* __restrict__ hw, const float* __restrict__ inv_in,
                              const int2* __restrict__ offs, const int* __restrict__ csr_src,
                              const float* __restrict__ bias, float* __restrict__ out, int n) {
    int t = threadIdx.x;
    int wave = t >> 6, lane = t & 63;
    int g = lane >> 3, gl = lane & 7;          // group 0..7, lane-in-group 0..7
    int row = blockIdx.x * 32 + wave * 8 + g;  // N = 3125 * 32 exactly
    if (row >= n) return;

    float acc0 = 0.f, acc1 = 0.f, acc2 = 0.f, acc3 = 0.f;
    float acc4 = 0.f, acc5 = 0.f, acc6 = 0.f, acc7 = 0.f;

    int2 oe = offs[row];
    int start = oe.x, end = oe.y;
    int gbase = g << 3;

    int jb = start;
    int mm = end - jb; if (mm > 8) mm = 8;
    int sidx = (mm > 0 && gl < mm) ? csr_src[jb + gl] : 0;

    while (jb < end) {
        int jb2 = jb + 8;
        int mm2 = end - jb2; if (mm2 > 8) mm2 = 8;
        int sidx2 = (jb2 < end && gl < mm2) ? csr_src[jb2 + gl] : 0;

        if (mm == 8) {
#pragma unroll
            for (int j = 0; j < 8; ++j) {
                int s = __shfl(sidx, gbase + j, 64);
                uint4 u = hw[(long long)s * 8 + gl];
                float2 f0 = __half22float2(*(__half2*)&u.x);
                float2 f1 = __half22float2(*(__half2*)&u.y);
                float2 f2 = __half22float2(*(__half2*)&u.z);
                float2 f3 = __half22float2(*(__half2*)&u.w);
                acc0 += f0.x; acc1 += f0.y; acc2 += f1.x; acc3 += f1.y;
                acc4 += f2.x; acc5 += f2.y; acc6 += f3.x; acc7 += f3.y;
            }
        } else {
            for (int j = 0; j < mm; ++j) {
                int s = __shfl(sidx, gbase + j, 64);
                uint4 u = hw[(long long)s * 8 + gl];
                float2 f0 = __half22float2(*(__half2*)&u.x);
                float2 f1 = __half22float2(*(__half2*)&u.y);
                float2 f2 = __half22float2(*(__half2*)&u.z);
                float2 f3 = __half22float2(*(__half2*)&u.w);
                acc0 += f0.x; acc1 += f0.y; acc2 += f1.x; acc3 += f1.y;
                acc4 += f2.x; acc5 += f2.y; acc6 += f3.x; acc7 += f3.y;
            }
        }
        jb = jb2; mm = mm2; sidx = sidx2;
    }

    float sc = inv_in[row];
    float4 b0 = ((const float4*)bias)[gl * 2 + 0];
    float4 b1 = ((const float4*)bias)[gl * 2 + 1];
    float4 r0, r1;
    r0.x = fmaxf(fmaf(acc0, sc, b0.x), 0.f);
    r0.y = fmaxf(fmaf(acc1, sc, b0.y), 0.f);
    r0.z = fmaxf(fmaf(acc2, sc, b0.z), 0.f);
    r0.w = fmaxf(fmaf(acc3, sc, b0.w), 0.f);
    r1.x = fmaxf(fmaf(acc4, sc, b1.x), 0.f);
    r1.y = fmaxf(fmaf(acc5, sc, b1.y), 0.f);
    r1.z = fmaxf(fmaf(acc6, sc, b1.z), 0.f);
    r1.w = fmaxf(fmaf(acc7, sc, b1.w), 0.f);
    ((float4*)out)[(long long)row * 16 + gl * 2 + 0] = r0;
    ((float4*)out)[(long long)row * 16 + gl * 2 + 1] = r1;
}

extern "C" void kernel_launch(void* const* d_in, const int* in_sizes, int n_in,
                              void* d_out, int out_size, void* d_ws, size_t ws_size,
                              hipStream_t stream) {
    const float* features = (const float*)d_in[0];   // [N, 64]
    const float* W        = (const float*)d_in[1];   // [64, 64]
    const float* b        = (const float*)d_in[2];   // [64]
    const int*   src      = (const int*)d_in[3];     // [E]
    const int*   dst      = (const int*)d_in[4];     // [E]

    float* out = (float*)d_out;                      // [N, 64] — also inter-layer temp

    // workspace layout (4-byte words); ~46 MB of 256 MB ws
    float* ws = (float*)d_ws;
    uint2* hw = (uint2*)ws;                                             // N*32 words = 12.8 MB
    unsigned int*   bufD = (unsigned int*)(ws + (size_t)N_NODES * 32);  // NBUCK*CAP words (12.85 MB)
    unsigned short* bufS = (unsigned short*)(bufD + (size_t)NBUCK * CAP); // NBUCK*CAP u16 (6.4 MB)
    int*   csr_src = (int*)(bufS + (size_t)NBUCK * CAP);                // NBUCK*CAP words (12.85 MB)
    int2*  offs    = (int2*)(csr_src + (size_t)NBUCK * CAP);            // N int2 (800 KB)
    float* inv_out = (float*)(offs + N_NODES);       // N
    float* inv_in  = inv_out + N_NODES;              // N
    int*   gcurD   = (int*)(inv_in + N_NODES);       // NBUCK
    int*   gcurS   = gcurD + NBUCK;                  // NBUCK

    const int N = N_NODES;

    // setup: fixed-capacity bucket sort (3 kernels, no memsets)
    init_kernel<<<1, 256, 0, stream>>>(gcurD, gcurS);
    place_kernel<<<NCHUNK, 256, 0, stream>>>(src, dst, gcurD, gcurS, bufD, bufS);
    bucket_kernel<<<2 * NBUCK, NPB, 0, stream>>>(bufD, bufS, gcurD, gcurS,
                                                 csr_src, offs, inv_in, inv_out);

    int dense_blocks  = (N + 31) / 32;
    int gather_blocks = (N + 31) / 32;   // 32 rows per block

    // layer 1: features -> hw(fp16) -> out
    dense_kernel<<<dense_blocks, 256, 0, stream>>>(features, inv_out, W, hw, N);
    gather_kernel<<<gather_blocks, 256, 0, stream>>>((const uint4*)hw, inv_in, offs, csr_src, b, out, N);

    // layer 2: out -> hw(fp16) -> out
    dense_kernel<<<dense_blocks, 256, 0, stream>>>(out, inv_out, W, hw, N);
    gather_kernel<<<gather_blocks, 256, 0, stream>>>((const uint4*)hw, inv_in, offs, csr_src, b, out, N);
}